// Round 4
// baseline (498.970 us; speedup 1.0000x reference)
//
#include <hip/hip_runtime.h>

#define N_NODES 50000
#define N_GRAPHS 512
#define N_EDGES 800000
#define NT 13          // src tiles: src>>12 in 0..12 (4096 rows = 2 MB window)
#define TILE_SHIFT 12

typedef __attribute__((ext_vector_type(8))) short short8;
typedef __attribute__((ext_vector_type(8))) unsigned short ushort8;
typedef __attribute__((ext_vector_type(4))) float floatx4;

__device__ __forceinline__ float bf2f(unsigned short u) {
    union { unsigned int i; float f; } c;
    c.i = ((unsigned int)u) << 16;
    return c.f;
}
__device__ __forceinline__ unsigned short f2bf(float f) {
    union { float f; unsigned int i; } c;
    c.f = f;
    unsigned int u = c.i;
    return (unsigned short)((u + 0x7fffu + ((u >> 16) & 1u)) >> 16);
}

// ---------------- fused converts: x (1.6M float4) + W1/W2/W3 (40960) -------
__global__ void convert_all(const float* __restrict__ x, const float* __restrict__ W1,
                            const float* __restrict__ W2, const float* __restrict__ W3,
                            unsigned short* __restrict__ xo, unsigned short* __restrict__ o1,
                            unsigned short* __restrict__ o2, unsigned short* __restrict__ o3) {
    int i = blockIdx.x * blockDim.x + threadIdx.x;  // 0..1640959
    const float* src; unsigned short* dst; int base;
    if (i < 1600000)      { src = x;  dst = xo; base = i; }
    else {
        int j = i - 1600000;
        if (j < 8192)       { src = W1; dst = o1; base = j; }
        else if (j < 24576) { src = W2; dst = o2; base = j - 8192; }
        else if (j < 40960) { src = W3; dst = o3; base = j - 24576; }
        else return;
    }
    float4 v = ((const float4*)src)[base];
    ushort4 o;
    o.x = f2bf(v.x); o.y = f2bf(v.y); o.z = f2bf(v.z); o.w = f2bf(v.w);
    ((ushort4*)dst)[base] = o;
}

// ---------------- CSR build (src-tiled sublists) ----------------
__global__ void deg_hist(const int* __restrict__ dst, int* __restrict__ deg) {
    int e = blockIdx.x * blockDim.x + threadIdx.x;
    if (e < N_EDGES) atomicAdd(&deg[dst[e]], 1);
}

// per-(dst, src-tile) histogram
__global__ void tile_hist(const int* __restrict__ src, const int* __restrict__ dst,
                          int* __restrict__ tcnt) {
    int e = blockIdx.x * blockDim.x + threadIdx.x;
    if (e < N_EDGES) {
        int s = src[e], d = dst[e];
        atomicAdd(&tcnt[d * NT + (s >> TILE_SHIFT)], 1);
    }
}

__global__ __launch_bounds__(1024) void scan1(const int* __restrict__ deg,
                                              int* __restrict__ rowptr,
                                              int* __restrict__ blocksum) {
    __shared__ int s[1024];
    int t = threadIdx.x;
    int i = blockIdx.x * 1024 + t;
    int v = (i < N_NODES) ? deg[i] : 0;
    s[t] = v;
    __syncthreads();
    for (int off = 1; off < 1024; off <<= 1) {
        int add = (t >= off) ? s[t - off] : 0;
        __syncthreads();
        s[t] += add;
        __syncthreads();
    }
    if (i < N_NODES) rowptr[i] = s[t] - v;  // exclusive
    if (t == 1023) blocksum[blockIdx.x] = s[t];
}

// wave-parallel exclusive scan of block sums (nb <= 64)
__global__ void scan2(int* __restrict__ blocksum, int nb) {
    int t = threadIdx.x;  // 64 threads, one wave
    int orig = (t < nb) ? blocksum[t] : 0;
    int v = orig;
    for (int off = 1; off < 64; off <<= 1) {
        int u = __shfl_up(v, off, 64);
        if (t >= off) v += u;
    }
    if (t < nb) blocksum[t] = v - orig;  // exclusive
}

__global__ void scan3(int* __restrict__ rowptr, const int* __restrict__ blocksum,
                      int* __restrict__ cursor) {
    int i = blockIdx.x * blockDim.x + threadIdx.x;
    if (i < N_NODES) {
        int v = rowptr[i] + blocksum[i >> 10];
        rowptr[i] = v;
        cursor[i] = v;
    }
    if (i == 0) rowptr[N_NODES] = N_EDGES;
}

// per-dst serial scan over the NT tile counts -> per-(dst,tile) cursors
__global__ void tile_scan(const int* __restrict__ rowptr, const int* __restrict__ tcnt,
                          int* __restrict__ tcur) {
    int d = blockIdx.x * blockDim.x + threadIdx.x;
    if (d >= N_NODES) return;
    int pos = rowptr[d];
#pragma unroll
    for (int t = 0; t < NT; t++) {
        int c = tcnt[d * NT + t];
        tcur[d * NT + t] = pos;
        pos += c;
    }
}

// scatter into (dst-major, src-tile-bucketed) CSR. Within a sublist the
// order is arbitrary (sum is order-independent); what matters is that a
// list's reads sweep src-space in 2 MB windows, in phase across blocks.
__global__ void scatter_tiled(const int* __restrict__ src, const int* __restrict__ dst,
                              int* __restrict__ tcur, int* __restrict__ csr) {
    int e = blockIdx.x * blockDim.x + threadIdx.x;
    if (e < N_EDGES) {
        int s = src[e], d = dst[e];
        int pos = atomicAdd(&tcur[d * NT + (s >> TILE_SHIFT)], 1);
        csr[pos] = s;
    }
}

// ---- bf16 gather (R0 proven config): 16B/lane, unroll-4 -------------------
template <int C>
__global__ __launch_bounds__(256) void gather_bf(const unsigned short* __restrict__ h,
                                                 const int* __restrict__ rowptr,
                                                 const int* __restrict__ csr,
                                                 unsigned short* __restrict__ agg) {
    const int TPN = C / 8;       // lanes per node (ushort8 = 16B each)
    const int NPB = 256 / TPN;
    int t = threadIdx.x;
    int n = blockIdx.x * NPB + t / TPN;
    if (n >= N_NODES) return;
    int c8 = t % TPN;
    const ushort8* hp = (const ushort8*)h + c8;
    ushort8 s = hp[(size_t)n * TPN];
    float acc[8];
#pragma unroll
    for (int j = 0; j < 8; j++) acc[j] = bf2f(s[j]);
    int p = rowptr[n], end = rowptr[n + 1];
    for (; p + 4 <= end; p += 4) {
        int j0 = csr[p], j1 = csr[p + 1], j2 = csr[p + 2], j3 = csr[p + 3];
        ushort8 v0 = hp[(size_t)j0 * TPN];
        ushort8 v1 = hp[(size_t)j1 * TPN];
        ushort8 v2 = hp[(size_t)j2 * TPN];
        ushort8 v3 = hp[(size_t)j3 * TPN];
#pragma unroll
        for (int j = 0; j < 8; j++)
            acc[j] += (bf2f(v0[j]) + bf2f(v1[j])) + (bf2f(v2[j]) + bf2f(v3[j]));
    }
    for (; p < end; ++p) {
        int jj = csr[p];
        ushort8 v = hp[(size_t)jj * TPN];
#pragma unroll
        for (int j = 0; j < 8; j++) acc[j] += bf2f(v[j]);
    }
    ushort8 o;
#pragma unroll
    for (int j = 0; j < 8; j++) o[j] = f2bf(acc[j]);
    ((ushort8*)agg)[(size_t)n * TPN + c8] = o;
}

// ---- barrier-free no-LDS MFMA GEMM ---------------------------------------
// out = relu(A[M,K]bf16 @ W[256,K]^T + b) -> bf16. BM=64, BN=256, 4 waves.
// A and W fragments straight from global: for one wave-load, lanes (lr,lkc)
// hit 16 rows x 64B fully-consumed lines (A just written -> L2/L3-resident;
// W 128KB L2-hot). No LDS, no barriers -> waves drift freely.
template <int K>
__global__ __launch_bounds__(256) void gemm_nolds(
    const unsigned short* __restrict__ A, const unsigned short* __restrict__ W,
    const float* __restrict__ bias, unsigned short* __restrict__ out, int M) {
    int tid = threadIdx.x;
    int wave = tid >> 6, lane = tid & 63;
    int lkc = lane >> 4, lr = lane & 15;
    int rowbase = blockIdx.x * 64;

    const short8* ap[4];
    const short8* wp[4];
#pragma unroll
    for (int mt = 0; mt < 4; mt++) {
        int r = rowbase + mt * 16 + lr;
        if (r >= M) r = M - 1;
        ap[mt] = (const short8*)(A + (size_t)r * K) + lkc;
    }
#pragma unroll
    for (int nt = 0; nt < 4; nt++)
        wp[nt] = (const short8*)(W + (size_t)(wave * 64 + nt * 16 + lr) * K) + lkc;

    floatx4 acc[4][4];
#pragma unroll
    for (int i = 0; i < 4; i++)
#pragma unroll
        for (int j = 0; j < 4; j++) acc[i][j] = (floatx4)(0.f);

#pragma unroll
    for (int k0 = 0; k0 < K; k0 += 32) {
        short8 af[4], wf[4];
#pragma unroll
        for (int mt = 0; mt < 4; mt++) af[mt] = ap[mt][k0 >> 3];
#pragma unroll
        for (int nt = 0; nt < 4; nt++) wf[nt] = wp[nt][k0 >> 3];
#pragma unroll
        for (int mt = 0; mt < 4; mt++)
#pragma unroll
            for (int nt = 0; nt < 4; nt++)
                acc[mt][nt] = __builtin_amdgcn_mfma_f32_16x16x32_bf16(
                    af[mt], wf[nt], acc[mt][nt], 0, 0, 0);
    }

    // C/D layout: col=lane&15, row=(lane>>4)*4+reg
#pragma unroll
    for (int mt = 0; mt < 4; mt++) {
#pragma unroll
        for (int reg = 0; reg < 4; reg++) {
            int row = rowbase + mt * 16 + lkc * 4 + reg;
            if (row >= M) continue;
#pragma unroll
            for (int nt = 0; nt < 4; nt++) {
                int col = wave * 64 + nt * 16 + lr;
                float v = acc[mt][nt][reg] + bias[col];
                out[(size_t)row * 256 + col] = f2bf(fmaxf(v, 0.f));
            }
        }
    }
}

// ------- mean pool, stage 1: streaming accumulate into fp32 sums -----------
// 1563 blocks x 32 rows, fully coalesced; batch sorted -> <=2 graph
// boundaries per chunk -> ~2 atomicAdds per thread.
__global__ __launch_bounds__(256) void pool_accum(const unsigned short* __restrict__ h,
                                                  const int* __restrict__ batch,
                                                  float* __restrict__ sums) {
    int t = threadIdx.x;  // column 0..255
    int r0 = blockIdx.x * 32;
    int r1 = r0 + 32; if (r1 > N_NODES) r1 = N_NODES;
    if (r0 >= N_NODES) return;
    float acc = 0.f;
    int gcur = batch[r0];
    for (int r = r0; r < r1; ++r) {
        int g = batch[r];
        if (g != gcur) { atomicAdd(&sums[gcur * 256 + t], acc); acc = 0.f; gcur = g; }
        acc += bf2f(h[(size_t)r * 256 + t]);
    }
    atomicAdd(&sums[gcur * 256 + t], acc);
}

// ------- mean pool, stage 2: divide + MLP head (one block per graph) -------
__global__ __launch_bounds__(128) void head(const float* __restrict__ sums,
                                            const int* __restrict__ batch,
                                            const float* __restrict__ Wf1,
                                            const float* __restrict__ bf1,
                                            const float* __restrict__ Wf2,
                                            const float* __restrict__ bf2,
                                            float* __restrict__ out) {
    __shared__ float hg[256];
    __shared__ float hid[128];
    int g = blockIdx.x;
    int t = threadIdx.x;
    int lo = 0, hi = N_NODES;
    while (lo < hi) { int m = (lo + hi) >> 1; if (batch[m] < g) lo = m + 1; else hi = m; }
    int start = lo;
    lo = 0; hi = N_NODES;
    while (lo < hi) { int m = (lo + hi) >> 1; if (batch[m] < g + 1) lo = m + 1; else hi = m; }
    int end = lo;
    float inv = 1.0f / fmaxf((float)(end - start), 1.0f);
    hg[t]       = sums[g * 256 + t] * inv;
    hg[t + 128] = sums[g * 256 + t + 128] * inv;
    __syncthreads();
    float a1 = bf1[t];
    for (int c = 0; c < 256; c++) a1 += hg[c] * Wf1[t * 256 + c];
    hid[t] = fmaxf(a1, 0.f);
    __syncthreads();
    if (t < 10) {
        float a = bf2[t];
        for (int j = 0; j < 128; j++) a += hid[j] * Wf2[t * 128 + j];
        out[g * 10 + t] = a;
    }
}

extern "C" void kernel_launch(void* const* d_in, const int* in_sizes, int n_in,
                              void* d_out, int out_size, void* d_ws, size_t ws_size,
                              hipStream_t stream) {
    const float* x   = (const float*)d_in[0];
    const int*  edge = (const int*)d_in[1];
    const int*  batch= (const int*)d_in[2];
    const float* W1  = (const float*)d_in[3];
    const float* b1  = (const float*)d_in[4];
    const float* W2  = (const float*)d_in[5];
    const float* b2  = (const float*)d_in[6];
    const float* W3  = (const float*)d_in[7];
    const float* b3  = (const float*)d_in[8];
    const float* Wf1 = (const float*)d_in[9];
    const float* bf1 = (const float*)d_in[10];
    const float* Wf2 = (const float*)d_in[11];
    const float* bf2 = (const float*)d_in[12];
    const int* src = edge;
    const int* dst = edge + N_EDGES;

    char* wsb = (char*)d_ws;
    size_t off = 0;
    auto alloc = [&](size_t bytes) { void* p = wsb + off; off += (bytes + 255) & ~(size_t)255; return p; };
    unsigned short* x_bf  = (unsigned short*)alloc((size_t)N_NODES * 128 * 2);
    unsigned short* agg_bf= (unsigned short*)alloc((size_t)N_NODES * 256 * 2);
    unsigned short* hA_bf = (unsigned short*)alloc((size_t)N_NODES * 256 * 2);
    unsigned short* hB_bf = (unsigned short*)alloc((size_t)N_NODES * 256 * 2);
    unsigned short* W1bf  = (unsigned short*)alloc(256 * 128 * 2);
    unsigned short* W2bf  = (unsigned short*)alloc(256 * 256 * 2);
    unsigned short* W3bf  = (unsigned short*)alloc(256 * 256 * 2);
    int* rowptr   = (int*)alloc((N_NODES + 4) * 4);
    int* deg      = (int*)alloc(N_NODES * 4);
    int* csr      = (int*)alloc(N_EDGES * 4);
    int* blocksum = (int*)alloc(64 * 4);
    // aliases into regions that are dead during their live ranges:
    int*   tcnt = (int*)hA_bf;     // live: memset..tile_scan (hA written at gemm L1)
    int*   tcur = (int*)agg_bf;    // live: tile_scan..scatter (agg written at gather L1)
    int*   cursor = deg;           // scan3 scratch (deg dead after scan1)
    float* sums = (float*)agg_bf;  // live: after gemm L3 (agg dead)

    const int NB_SCAN = (N_NODES + 1023) / 1024;  // 49

    // ---- CSR build (dst-major, src-tile-bucketed) ----
    hipMemsetAsync(deg, 0, N_NODES * sizeof(int), stream);
    hipMemsetAsync(tcnt, 0, (size_t)N_NODES * NT * sizeof(int), stream);
    deg_hist<<<(N_EDGES + 255) / 256, 256, 0, stream>>>(dst, deg);
    tile_hist<<<(N_EDGES + 255) / 256, 256, 0, stream>>>(src, dst, tcnt);
    scan1<<<NB_SCAN, 1024, 0, stream>>>(deg, rowptr, blocksum);
    scan2<<<1, 64, 0, stream>>>(blocksum, NB_SCAN);
    scan3<<<NB_SCAN, 1024, 0, stream>>>(rowptr, blocksum, cursor);
    tile_scan<<<(N_NODES + 255) / 256, 256, 0, stream>>>(rowptr, tcnt, tcur);
    scatter_tiled<<<(N_EDGES + 255) / 256, 256, 0, stream>>>(src, dst, tcur, csr);

    // ---- converts (x + all weights, one launch) ----
    convert_all<<<(1640960 + 255) / 256, 256, 0, stream>>>(x, W1, W2, W3, x_bf, W1bf, W2bf, W3bf);

    const int NB_GEMM = (N_NODES + 63) / 64;  // 782

    // ---- layer 1 (K=128) ----
    gather_bf<128><<<(N_NODES + 15) / 16, 256, 0, stream>>>(x_bf, rowptr, csr, agg_bf);
    gemm_nolds<128><<<NB_GEMM, 256, 0, stream>>>(agg_bf, W1bf, b1, hA_bf, N_NODES);

    // ---- layer 2 (K=256) ----
    gather_bf<256><<<(N_NODES + 7) / 8, 256, 0, stream>>>(hA_bf, rowptr, csr, agg_bf);
    gemm_nolds<256><<<NB_GEMM, 256, 0, stream>>>(agg_bf, W2bf, b2, hB_bf, N_NODES);

    // ---- layer 3 (K=256) ----
    gather_bf<256><<<(N_NODES + 7) / 8, 256, 0, stream>>>(hB_bf, rowptr, csr, agg_bf);
    gemm_nolds<256><<<NB_GEMM, 256, 0, stream>>>(agg_bf, W3bf, b3, hA_bf, N_NODES);

    // ---- mean pool (streaming accumulate) + head ----
    hipMemsetAsync(sums, 0, (size_t)N_GRAPHS * 256 * sizeof(float), stream);
    pool_accum<<<(N_NODES + 31) / 32, 256, 0, stream>>>(hA_bf, batch, sums);
    head<<<N_GRAPHS, 128, 0, stream>>>(sums, batch, Wf1, bf1, Wf2, bf2, (float*)d_out);
}

// Round 5
// 446.809 us; speedup vs baseline: 1.1167x; 1.1167x over previous
//
#include <hip/hip_runtime.h>

#define N_NODES 50000
#define N_GRAPHS 512
#define N_EDGES 800000

typedef __attribute__((ext_vector_type(8))) short short8;
typedef __attribute__((ext_vector_type(8))) unsigned short ushort8;
typedef __attribute__((ext_vector_type(4))) float floatx4;

__device__ __forceinline__ float bf2f(unsigned short u) {
    union { unsigned int i; float f; } c;
    c.i = ((unsigned int)u) << 16;
    return c.f;
}
__device__ __forceinline__ unsigned short f2bf(float f) {
    union { float f; unsigned int i; } c;
    c.f = f;
    unsigned int u = c.i;
    return (unsigned short)((u + 0x7fffu + ((u >> 16) & 1u)) >> 16);
}

// async 16B global -> LDS (lane-ordered destination: ldsbase + lane*16)
__device__ __forceinline__ void g2lds16(const unsigned short* g, void* lds) {
    __builtin_amdgcn_global_load_lds(
        (const __attribute__((address_space(1))) void*)g,
        (__attribute__((address_space(3))) void*)lds, 16, 0, 0);
}

// ---------------- fused converts: x (1.6M float4) + W1/W2/W3 (40960) -------
__global__ void convert_all(const float* __restrict__ x, const float* __restrict__ W1,
                            const float* __restrict__ W2, const float* __restrict__ W3,
                            unsigned short* __restrict__ xo, unsigned short* __restrict__ o1,
                            unsigned short* __restrict__ o2, unsigned short* __restrict__ o3) {
    int i = blockIdx.x * blockDim.x + threadIdx.x;  // 0..1640959
    const float* src; unsigned short* dst; int base;
    if (i < 1600000)      { src = x;  dst = xo; base = i; }
    else {
        int j = i - 1600000;
        if (j < 8192)       { src = W1; dst = o1; base = j; }
        else if (j < 24576) { src = W2; dst = o2; base = j - 8192; }
        else if (j < 40960) { src = W3; dst = o3; base = j - 24576; }
        else return;
    }
    float4 v = ((const float4*)src)[base];
    ushort4 o;
    o.x = f2bf(v.x); o.y = f2bf(v.y); o.z = f2bf(v.z); o.w = f2bf(v.w);
    ((ushort4*)dst)[base] = o;
}

// ---------------- CSR build ----------------
__global__ void deg_hist(const int* __restrict__ dst, int* __restrict__ deg) {
    int e = blockIdx.x * blockDim.x + threadIdx.x;
    if (e < N_EDGES) atomicAdd(&deg[dst[e]], 1);
}

__global__ __launch_bounds__(1024) void scan1(const int* __restrict__ deg,
                                              int* __restrict__ rowptr,
                                              int* __restrict__ blocksum) {
    __shared__ int s[1024];
    int t = threadIdx.x;
    int i = blockIdx.x * 1024 + t;
    int v = (i < N_NODES) ? deg[i] : 0;
    s[t] = v;
    __syncthreads();
    for (int off = 1; off < 1024; off <<= 1) {
        int add = (t >= off) ? s[t - off] : 0;
        __syncthreads();
        s[t] += add;
        __syncthreads();
    }
    if (i < N_NODES) rowptr[i] = s[t] - v;  // exclusive
    if (t == 1023) blocksum[blockIdx.x] = s[t];
}

// wave-parallel exclusive scan of block sums (nb <= 64)
__global__ void scan2(int* __restrict__ blocksum, int nb) {
    int t = threadIdx.x;  // 64 threads, one wave
    int orig = (t < nb) ? blocksum[t] : 0;
    int v = orig;
    for (int off = 1; off < 64; off <<= 1) {
        int u = __shfl_up(v, off, 64);
        if (t >= off) v += u;
    }
    if (t < nb) blocksum[t] = v - orig;  // exclusive
}

__global__ void scan3(int* __restrict__ rowptr, const int* __restrict__ blocksum,
                      int* __restrict__ cursor) {
    int i = blockIdx.x * blockDim.x + threadIdx.x;
    if (i < N_NODES) {
        int v = rowptr[i] + blocksum[i >> 10];
        rowptr[i] = v;
        cursor[i] = v;
    }
    if (i == 0) rowptr[N_NODES] = N_EDGES;
}

__global__ void scatter_csr(const int* __restrict__ src, const int* __restrict__ dst,
                            int* __restrict__ cursor, int* __restrict__ csr) {
    int e = blockIdx.x * blockDim.x + threadIdx.x;
    if (e < N_EDGES) {
        int pos = atomicAdd(&cursor[dst[e]], 1);
        csr[pos] = src[e];
    }
}

// ---- bf16 gather: R0 inner loop, grid-stride persistent blocks ------------
// R4 showed occupancy stuck at 66% with 6250 short-lived (~2 us) blocks:
// workgroup churn keeps time-averaged residency at ~21/32 waves. Grid=2048
// (exactly 8 blocks/CU, VGPR 28, LDS 0) persists blocks for the whole
// kernel; BW ∝ resident gather waves (R1/R2 calibration).
template <int C>
__global__ __launch_bounds__(256) void gather_bf(const unsigned short* __restrict__ h,
                                                 const int* __restrict__ rowptr,
                                                 const int* __restrict__ csr,
                                                 unsigned short* __restrict__ agg) {
    const int TPN = C / 8;       // lanes per node (ushort8 = 16B each)
    const int NPB = 256 / TPN;
    const int NCHUNK = (N_NODES + NPB - 1) / NPB;
    int t = threadIdx.x;
    int g = t / TPN, c8 = t % TPN;
    const ushort8* hp = (const ushort8*)h + c8;
    for (int blk = blockIdx.x; blk < NCHUNK; blk += gridDim.x) {
        int n = blk * NPB + g;
        if (n >= N_NODES) continue;
        ushort8 s = hp[(size_t)n * TPN];
        float acc[8];
#pragma unroll
        for (int j = 0; j < 8; j++) acc[j] = bf2f(s[j]);
        int p = rowptr[n], end = rowptr[n + 1];
        for (; p + 4 <= end; p += 4) {
            int j0 = csr[p], j1 = csr[p + 1], j2 = csr[p + 2], j3 = csr[p + 3];
            ushort8 v0 = hp[(size_t)j0 * TPN];
            ushort8 v1 = hp[(size_t)j1 * TPN];
            ushort8 v2 = hp[(size_t)j2 * TPN];
            ushort8 v3 = hp[(size_t)j3 * TPN];
#pragma unroll
            for (int j = 0; j < 8; j++)
                acc[j] += (bf2f(v0[j]) + bf2f(v1[j])) + (bf2f(v2[j]) + bf2f(v3[j]));
        }
        for (; p < end; ++p) {
            int jj = csr[p];
            ushort8 v = hp[(size_t)jj * TPN];
#pragma unroll
            for (int j = 0; j < 8; j++) acc[j] += bf2f(v[j]);
        }
        ushort8 o;
#pragma unroll
        for (int j = 0; j < 8; j++) o[j] = f2bf(acc[j]);
        ((ushort8*)agg)[(size_t)n * TPN + c8] = o;
    }
}

// ---- MFMA GEMM with global_load_lds staging (R0 proven) -------------------
// out = relu(A[M,K]bf16 @ W[256,K]bf16^T + b) -> bf16. BM=128, BN=128
// (blockIdx.y in {0,1}), BK=32, 256 threads = 4 waves (2x2).
template <int K>
__global__ __launch_bounds__(256) void gemm_mfma(
    const unsigned short* __restrict__ A, const unsigned short* __restrict__ W,
    const float* __restrict__ bias, unsigned short* __restrict__ Cbf, int M) {
    __shared__ short8 As[512];  // 8 KB
    __shared__ short8 Ws[512];  // 8 KB

    int tid = threadIdx.x;
    int wave = tid >> 6, lane = tid & 63;
    int wm = wave & 1, wn = wave >> 1;
    int rowbase = blockIdx.x * 128;
    int colbase = blockIdx.y * 128;
    int lkc = lane >> 4, lr = lane & 15;
    int rslot = lkc * 16 + (lr ^ (lkc << 2));

    int rsw = lr ^ (lkc << 2);
    int row0 = (0 * 4 + wave) * 16 + rsw;
    int row1 = (1 * 4 + wave) * 16 + rsw;
    int ar0 = rowbase + row0; if (ar0 >= M) ar0 = M - 1;
    int ar1 = rowbase + row1; if (ar1 >= M) ar1 = M - 1;
    int wr0 = colbase + row0;
    int wr1 = colbase + row1;
    char* asb0 = (char*)As + (size_t)(0 * 256 + wave * 64) * 16;
    char* asb1 = (char*)As + (size_t)(1 * 256 + wave * 64) * 16;
    char* wsb0 = (char*)Ws + (size_t)(0 * 256 + wave * 64) * 16;
    char* wsb1 = (char*)Ws + (size_t)(1 * 256 + wave * 64) * 16;

    floatx4 acc[4][4];
#pragma unroll
    for (int i = 0; i < 4; i++)
#pragma unroll
        for (int j = 0; j < 4; j++) acc[i][j] = (floatx4)(0.f);

#pragma unroll 2
    for (int k0 = 0; k0 < K; k0 += 32) {
        int ks = k0 + lkc * 8;
        g2lds16(A + (size_t)ar0 * K + ks, asb0);
        g2lds16(A + (size_t)ar1 * K + ks, asb1);
        g2lds16(W + (size_t)wr0 * K + ks, wsb0);
        g2lds16(W + (size_t)wr1 * K + ks, wsb1);
        __syncthreads();

        short8 af[4], wf[4];
#pragma unroll
        for (int mt = 0; mt < 4; mt++) af[mt] = As[(wm * 4 + mt) * 64 + rslot];
#pragma unroll
        for (int nt = 0; nt < 4; nt++) wf[nt] = Ws[(wn * 4 + nt) * 64 + rslot];
#pragma unroll
        for (int mt = 0; mt < 4; mt++)
#pragma unroll
            for (int nt = 0; nt < 4; nt++)
                acc[mt][nt] = __builtin_amdgcn_mfma_f32_16x16x32_bf16(
                    af[mt], wf[nt], acc[mt][nt], 0, 0, 0);
        __syncthreads();
    }

    // C/D layout: col=lane&15, row=(lane>>4)*4+reg
    int ccol = lr;
    int r0 = lkc * 4;
#pragma unroll
    for (int mt = 0; mt < 4; mt++) {
#pragma unroll
        for (int reg = 0; reg < 4; reg++) {
            int row = rowbase + (wm * 4 + mt) * 16 + r0 + reg;
            if (row >= M) continue;
#pragma unroll
            for (int nt = 0; nt < 4; nt++) {
                int col = colbase + (wn * 4 + nt) * 16 + ccol;
                float v = acc[mt][nt][reg] + bias[col];
                Cbf[(size_t)row * 256 + col] = f2bf(fmaxf(v, 0.f));
            }
        }
    }
}

// ------- mean pool, stage 1: streaming accumulate into fp32 sums -----------
// 1563 blocks x 32 rows, fully coalesced; batch sorted -> <=2 graph
// boundaries per chunk -> ~2 atomicAdds per thread.
__global__ __launch_bounds__(256) void pool_accum(const unsigned short* __restrict__ h,
                                                  const int* __restrict__ batch,
                                                  float* __restrict__ sums) {
    int t = threadIdx.x;  // column 0..255
    int r0 = blockIdx.x * 32;
    int r1 = r0 + 32; if (r1 > N_NODES) r1 = N_NODES;
    if (r0 >= N_NODES) return;
    float acc = 0.f;
    int gcur = batch[r0];
    for (int r = r0; r < r1; ++r) {
        int g = batch[r];
        if (g != gcur) { atomicAdd(&sums[gcur * 256 + t], acc); acc = 0.f; gcur = g; }
        acc += bf2f(h[(size_t)r * 256 + t]);
    }
    atomicAdd(&sums[gcur * 256 + t], acc);
}

// ------- mean pool, stage 2: divide + MLP head (one block per graph) -------
__global__ __launch_bounds__(128) void head(const float* __restrict__ sums,
                                            const int* __restrict__ batch,
                                            const float* __restrict__ Wf1,
                                            const float* __restrict__ bf1,
                                            const float* __restrict__ Wf2,
                                            const float* __restrict__ bf2,
                                            float* __restrict__ out) {
    __shared__ float hg[256];
    __shared__ float hid[128];
    int g = blockIdx.x;
    int t = threadIdx.x;
    int lo = 0, hi = N_NODES;
    while (lo < hi) { int m = (lo + hi) >> 1; if (batch[m] < g) lo = m + 1; else hi = m; }
    int start = lo;
    lo = 0; hi = N_NODES;
    while (lo < hi) { int m = (lo + hi) >> 1; if (batch[m] < g + 1) lo = m + 1; else hi = m; }
    int end = lo;
    float inv = 1.0f / fmaxf((float)(end - start), 1.0f);
    hg[t]       = sums[g * 256 + t] * inv;
    hg[t + 128] = sums[g * 256 + t + 128] * inv;
    __syncthreads();
    float a1 = bf1[t];
    for (int c = 0; c < 256; c++) a1 += hg[c] * Wf1[t * 256 + c];
    hid[t] = fmaxf(a1, 0.f);
    __syncthreads();
    if (t < 10) {
        float a = bf2[t];
        for (int j = 0; j < 128; j++) a += hid[j] * Wf2[t * 128 + j];
        out[g * 10 + t] = a;
    }
}

extern "C" void kernel_launch(void* const* d_in, const int* in_sizes, int n_in,
                              void* d_out, int out_size, void* d_ws, size_t ws_size,
                              hipStream_t stream) {
    const float* x   = (const float*)d_in[0];
    const int*  edge = (const int*)d_in[1];
    const int*  batch= (const int*)d_in[2];
    const float* W1  = (const float*)d_in[3];
    const float* b1  = (const float*)d_in[4];
    const float* W2  = (const float*)d_in[5];
    const float* b2  = (const float*)d_in[6];
    const float* W3  = (const float*)d_in[7];
    const float* b3  = (const float*)d_in[8];
    const float* Wf1 = (const float*)d_in[9];
    const float* bf1 = (const float*)d_in[10];
    const float* Wf2 = (const float*)d_in[11];
    const float* bf2 = (const float*)d_in[12];
    const int* src = edge;
    const int* dst = edge + N_EDGES;

    char* wsb = (char*)d_ws;
    size_t off = 0;
    auto alloc = [&](size_t bytes) { void* p = wsb + off; off += (bytes + 255) & ~(size_t)255; return p; };
    unsigned short* x_bf  = (unsigned short*)alloc((size_t)N_NODES * 128 * 2);
    unsigned short* agg_bf= (unsigned short*)alloc((size_t)N_NODES * 256 * 2);
    unsigned short* hA_bf = (unsigned short*)alloc((size_t)N_NODES * 256 * 2);
    unsigned short* hB_bf = (unsigned short*)alloc((size_t)N_NODES * 256 * 2);
    unsigned short* W1bf  = (unsigned short*)alloc(256 * 128 * 2);
    unsigned short* W2bf  = (unsigned short*)alloc(256 * 256 * 2);
    unsigned short* W3bf  = (unsigned short*)alloc(256 * 256 * 2);
    int* rowptr   = (int*)alloc((N_NODES + 4) * 4);
    int* cursor   = (int*)alloc(N_NODES * 4);
    int* deg      = (int*)alloc(N_NODES * 4);
    int* csr      = (int*)alloc(N_EDGES * 4);
    int* blocksum = (int*)alloc(64 * 4);
    // sums aliases agg_bf: agg is dead after gemm L3 consumes it.
    float* sums = (float*)agg_bf;

    const int NB_SCAN = (N_NODES + 1023) / 1024;  // 49

    // ---- CSR build (by dst) ----
    hipMemsetAsync(deg, 0, N_NODES * sizeof(int), stream);
    deg_hist<<<(N_EDGES + 255) / 256, 256, 0, stream>>>(dst, deg);
    scan1<<<NB_SCAN, 1024, 0, stream>>>(deg, rowptr, blocksum);
    scan2<<<1, 64, 0, stream>>>(blocksum, NB_SCAN);
    scan3<<<NB_SCAN, 1024, 0, stream>>>(rowptr, blocksum, cursor);
    scatter_csr<<<(N_EDGES + 255) / 256, 256, 0, stream>>>(src, dst, cursor, csr);

    // ---- converts (x + all weights, one launch) ----
    convert_all<<<(1640960 + 255) / 256, 256, 0, stream>>>(x, W1, W2, W3, x_bf, W1bf, W2bf, W3bf);

    dim3 ggrid((N_NODES + 127) / 128, 2);  // 391 x 2
    const int GATHER_GRID = 2048;          // 8 persistent blocks/CU

    // ---- layer 1 (K=128) ----
    gather_bf<128><<<GATHER_GRID, 256, 0, stream>>>(x_bf, rowptr, csr, agg_bf);
    gemm_mfma<128><<<ggrid, 256, 0, stream>>>(agg_bf, W1bf, b1, hA_bf, N_NODES);

    // ---- layer 2 (K=256) ----
    gather_bf<256><<<GATHER_GRID, 256, 0, stream>>>(hA_bf, rowptr, csr, agg_bf);
    gemm_mfma<256><<<ggrid, 256, 0, stream>>>(agg_bf, W2bf, b2, hB_bf, N_NODES);

    // ---- layer 3 (K=256) ----
    gather_bf<256><<<GATHER_GRID, 256, 0, stream>>>(hB_bf, rowptr, csr, agg_bf);
    gemm_mfma<256><<<ggrid, 256, 0, stream>>>(agg_bf, W3bf, b3, hA_bf, N_NODES);

    // ---- mean pool (streaming accumulate) + head ----
    hipMemsetAsync(sums, 0, (size_t)N_GRAPHS * 256 * sizeof(float), stream);
    pool_accum<<<(N_NODES + 31) / 32, 256, 0, stream>>>(hA_bf, batch, sums);
    head<<<N_GRAPHS, 128, 0, stream>>>(sums, batch, Wf1, bf1, Wf2, bf2, (float*)d_out);
}